// Round 2
// 13417.050 us; speedup vs baseline: 1.0118x; 1.0118x over previous
//
#include <hip/hip_runtime.h>
#include <stdint.h>

#define LL 4
#define BATCH 128
#define TSEQ 1024
#define HID 512
#define G4 2048
#define NG 4      // pipelined kernel: batch groups (32 batches each)
#define BBQ 32    // pipelined kernel: batches per group (2 MFMA row-tiles)
#define KAPS 32   // hidden-slice WGs per group (16 cols each)
#define RING 8    // per-layer h ring depth (power of 2)

typedef __attribute__((ext_vector_type(8))) short s8v;   // 8 x bf16 fragment
typedef __attribute__((ext_vector_type(4))) float f4v;   // MFMA accumulator

__device__ __forceinline__ unsigned short f2bf(float f) {
  union { float f; unsigned u; } v; v.f = f;
  return (unsigned short)((v.u + 0x7fffu + ((v.u >> 16) & 1u)) >> 16);  // RNE
}

__device__ __forceinline__ float fsig(float x) { return 1.f / (1.f + __expf(-x)); }

__device__ __forceinline__ float ftanh(float x) {
  float a = __builtin_fabsf(x);
  float e = __expf(-2.f * a);
  float t = (1.f - e) / (1.f + e);
  return x < 0.f ? -t : t;
}

__global__ void cvt_f32_bf16(const float* __restrict__ in, unsigned short* __restrict__ out, int n4) {
  int stride = gridDim.x * blockDim.x;
  for (int i = blockIdx.x * blockDim.x + threadIdx.x; i < n4; i += stride) {
    f4v v = ((const f4v*)in)[i];
    union { unsigned short u[4]; unsigned long long d; } o;
    o.u[0] = f2bf(v.x); o.u[1] = f2bf(v.y); o.u[2] = f2bf(v.z); o.u[3] = f2bf(v.w);
    ((unsigned long long*)out)[i] = o.d;
  }
}

// Bounded flag spin: per-lane flag index + target, wave-wide __all.
// Guard expiry -> wrong answer, never a hang.
__device__ __forceinline__ void pollv(const unsigned int* p, int idx, int tgt) {
  for (int guard = 0; guard < (1 << 17); ++guard) {
    unsigned f = __hip_atomic_load(&p[idx], __ATOMIC_RELAXED, __HIP_MEMORY_SCOPE_AGENT);
    if (__all((int)f >= tgt)) break;
  }
  asm volatile("" ::: "memory");  // no compiler motion of data loads above the poll
}

// One K=256 half of a 16-row GEMM fragment: 8 K-fragments x 4 gate-tiles.
template<bool ATOM>
__device__ __forceinline__ void mmfrag(const unsigned short* p, const s8v (&breg)[4][8], f4v (&acc)[4]) {
  union { unsigned long long q[16]; s8v v[8]; } ua;
  if (ATOM) {
    const unsigned long long* b64 = (const unsigned long long*)p;
#pragma unroll
    for (int s = 0; s < 8; ++s) {
      ua.q[2 * s]     = __hip_atomic_load(b64 + s * 8,     __ATOMIC_RELAXED, __HIP_MEMORY_SCOPE_AGENT);
      ua.q[2 * s + 1] = __hip_atomic_load(b64 + s * 8 + 1, __ATOMIC_RELAXED, __HIP_MEMORY_SCOPE_AGENT);
    }
  } else {
#pragma unroll
    for (int s = 0; s < 8; ++s) ua.v[s] = *(const s8v*)(p + s * 32);
  }
#pragma unroll
  for (int s = 0; s < 8; ++s)
#pragma unroll
    for (int g = 0; g < 4; ++g)
      acc[g] = __builtin_amdgcn_mfma_f32_16x16x32_bf16(ua.v[s], breg[g][s], acc[g], 0, 0, 0);
}

// Two 16-batch row tiles -> partial[32][64] (D layout m89: col=lane&15, row=quad*4+reg)
template<bool ATOM>
__device__ __forceinline__ void gemm32(
    const unsigned short* __restrict__ base, size_t rstride,
    int bg0, int lm, int quad, int koffA,
    const s8v (&breg)[4][8], float (*dst)[64])
{
#pragma unroll
  for (int bt = 0; bt < 2; ++bt) {
    const unsigned short* p = base + (size_t)(bg0 + bt * 16 + lm) * rstride + koffA;
    f4v acc[4];
#pragma unroll
    for (int g = 0; g < 4; ++g) { f4v z = {0.f, 0.f, 0.f, 0.f}; acc[g] = z; }
    mmfrag<ATOM>(p, breg, acc);
#pragma unroll
    for (int g = 0; g < 4; ++g)
#pragma unroll
      for (int r2 = 0; r2 < 4; ++r2)
        dst[bt * 16 + quad * 4 + r2][g * 16 + lm] = acc[g][r2];
  }
}

// All-4-layers pipelined persistent LSTM (no-prefetch schedule, 32KB LDS).
//  512 WGs = 4 layers x (4 groups x 32 hidden slices); 2 WGs/CU co-resident.
//  waves 0-1 ("x waves"): compute x-partial for THIS step t; layers >=1 read
//    upstream ring slot t&7 gated by upf >= t+2 (upstream completed step t).
//  waves 2-3 ("h waves"): fused poll: lanes 0-31 ownf >= t+1 (group finished
//    step t-1); lanes 32-63 dnf >= t-6 (downstream finished its read of the
//    slot t&7 we are about to overwrite, i.e. its step t-8).
//  Write of h(t) happens after syncA, so it is gated by both polls.
//  Flag protocol: syncB drains all h stores (vmcnt(0)+s_barrier), then tid0
//    stores flag = t+2 (agent-scope; h data committed to LLC before flag).
__global__ void __launch_bounds__(256, 2) lstm_all(
    const unsigned short* __restrict__ xin,   // (B,T,512) bf16, layer-0 input
    const unsigned short* __restrict__ wihb,  // (L,2048,512) bf16
    const unsigned short* __restrict__ whhb,  // (L,2048,512) bf16
    const float* __restrict__ bih,            // (L,2048)
    const float* __restrict__ bhh,            // (L,2048)
    const float* __restrict__ h0,             // (L,B,512) fp32
    const float* __restrict__ c0,             // (L,B,512) fp32
    unsigned short* __restrict__ ring,        // L * RING * B * 512 bf16
    unsigned int* __restrict__ bars,          // L*NG*KAPS epoch flags (zeroed)
    float* __restrict__ cout)                 // (L,B,512) fp32 final c
{
  const int tid  = threadIdx.x;
  const int wave = tid >> 6;
  const int lane = tid & 63;
  const int lm   = lane & 15;
  const int quad = lane >> 4;

  const int bid = blockIdx.x;
  const int lay = bid >> 7;       // 128 WGs per layer
  const int rr  = bid & 127;
  const int grp = rr & 3;
  const int kap = rr >> 2;        // hidden slice 0..31
  const int bg0 = grp * BBQ;

  __shared__ float xpart[2][BBQ][64];   // [x wave][batch][gate] (current step)
  __shared__ float hpart[2][BBQ][64];   // [h wave][batch][gate]

  const int isH = (wave >= 2);
  const unsigned short* wsel = (isH ? whhb : wihb) + (size_t)lay * G4 * HID;
  const int kbase = (wave & 1) * 256;

  // ---- weight fragments resident for all 1024 steps (128 regs/lane) ----
  s8v breg[4][8];
#pragma unroll
  for (int g = 0; g < 4; ++g) {
    const size_t row = (size_t)(g * 512 + kap * 16 + lm);
#pragma unroll
    for (int s = 0; s < 8; ++s)
      breg[g][s] = *(const s8v*)(wsel + row * HID + kbase + s * 32 + quad * 8);
  }

  // ---- per-thread cell ownership: 2 cells (batches bi0, bi0+16) x col kcol ----
  const int bi0  = tid >> 4;
  const int kk   = tid & 15;
  const int kcol = kap * 16 + kk;

  float bias[4];
#pragma unroll
  for (int g = 0; g < 4; ++g)
    bias[g] = bih[lay * G4 + g * 512 + kcol] + bhh[lay * G4 + g * 512 + kcol];

  unsigned short* ringL = ring + (size_t)lay * RING * BATCH * HID;
  const unsigned short* ringUp = ring + (size_t)(lay - 1) * RING * BATCH * HID;

  // publish h0 = h(-1) into ring slot RING-1 through the coherence point
  float c[2];
#pragma unroll
  for (int j = 0; j < 2; ++j) {
    const int brow = bg0 + bi0 + j * 16;
    c[j] = c0[(size_t)lay * BATCH * HID + (size_t)brow * HID + kcol];
    unsigned short hb0 = f2bf(h0[(size_t)lay * BATCH * HID + (size_t)brow * HID + kcol]);
    unsigned hw0 = (unsigned)hb0 | (((unsigned)(unsigned short)__shfl_xor((int)hb0, 1, 64)) << 16);
    if ((tid & 1) == 0)
      __hip_atomic_store((unsigned*)(ringL + (size_t)(RING - 1) * BATCH * HID)
                             + (size_t)brow * (HID / 2) + (kcol >> 1),
                         hw0, __ATOMIC_RELAXED, __HIP_MEMORY_SCOPE_AGENT);
  }

  unsigned int* ownf = bars + ((lay * NG + grp) << 5);
  unsigned int* upf  = ownf - (NG << 5);   // deref'd only lay>0
  unsigned int* dnf  = ownf + (NG << 5);   // deref'd only lay<LL-1

  const int koffA = kbase + quad * 8;

  __syncthreads();                   // drains h0 stores of every wave
  if (tid == 0)
    __hip_atomic_store(&ownf[kap], 1u, __ATOMIC_RELAXED, __HIP_MEMORY_SCOPE_AGENT);

  for (int t = 0; t < TSEQ; ++t) {
    if (!isH) {
      // ---- x waves: partial for step t (parallel with h waves' poll+GEMM) ----
      if (lay > 0) {
        pollv(upf, lane & 31, t + 2);   // upstream completed step t -> h_up(t) ready
        gemm32<true>(ringUp + (size_t)(t & (RING - 1)) * BATCH * HID,
                     (size_t)HID, bg0, lm, quad, koffA, breg, xpart[wave]);
      } else {
        gemm32<false>(xin + (size_t)t * HID, (size_t)TSEQ * HID,
                      bg0, lm, quad, koffA, breg, xpart[wave]);
      }
    } else {
      // ---- h waves: fused poll (own epoch + downstream back-pressure) ----
      const bool ownside = (lane < 32) || (lay == LL - 1);
      pollv(ownside ? ownf : dnf, lane & 31, ownside ? (t + 1) : (t - 6));
      gemm32<true>(ringL + (size_t)((t - 1) & (RING - 1)) * BATCH * HID,
                   (size_t)HID, bg0, lm, quad, koffA, breg, hpart[wave - 2]);
    }

    __syncthreads();   // sync A: partials visible; all polls passed

    unsigned short hbv[2];
#pragma unroll
    for (int j = 0; j < 2; ++j) {
      const int bi = bi0 + j * 16;
      float gs[4];
#pragma unroll
      for (int g = 0; g < 4; ++g)
        gs[g] = bias[g]
              + xpart[0][bi][g * 16 + kk] + xpart[1][bi][g * 16 + kk]
              + hpart[0][bi][g * 16 + kk] + hpart[1][bi][g * 16 + kk];
      float ig = fsig(gs[0]);
      float fg = fsig(gs[1]);
      float gg = ftanh(gs[2]);
      float og = fsig(gs[3]);
      c[j] = fg * c[j] + ig * gg;
      hbv[j] = f2bf(og * ftanh(c[j]));
    }

    // publish h(t) into ring slot t&7 (recurrent readers + downstream layer)
    unsigned short* hdst = ringL + (size_t)(t & (RING - 1)) * BATCH * HID;
#pragma unroll
    for (int j = 0; j < 2; ++j) {
      unsigned hw = (unsigned)hbv[j] | (((unsigned)(unsigned short)__shfl_xor((int)hbv[j], 1, 64)) << 16);
      if ((tid & 1) == 0)
        __hip_atomic_store((unsigned*)hdst + (size_t)(bg0 + bi0 + j * 16) * (HID / 2) + (kcol >> 1),
                           hw, __ATOMIC_RELAXED, __HIP_MEMORY_SCOPE_AGENT);
    }

    __syncthreads();   // sync B: every wave's h stores drained (vmcnt(0)+s_barrier)
    if (tid == 0)
      __hip_atomic_store(&ownf[kap], (unsigned)(t + 2), __ATOMIC_RELAXED,
                         __HIP_MEMORY_SCOPE_AGENT);
  }

#pragma unroll
  for (int j = 0; j < 2; ++j)
    cout[(size_t)lay * BATCH * HID + (size_t)(bg0 + bi0 + j * 16) * HID + kcol] = c[j];
}

// ---------------------------------------------------------------------------
// Fallback: the proven R4 per-layer kernel (verbatim; passes at ~13.6 ms).
// Used only if the cooperative capacity check / launch denies the 512-WG
// pipelined kernel.
// ---------------------------------------------------------------------------
__global__ void __launch_bounds__(256, 1) lstm_layer(
    const unsigned short* __restrict__ xin,   // (B,T,512) bf16 layer input
    unsigned short* __restrict__ seqout,      // (B,T,512) bf16 layer output
    const unsigned short* __restrict__ wih,   // (2048,512) bf16
    const unsigned short* __restrict__ whh,   // (2048,512) bf16
    const float* __restrict__ bih,
    const float* __restrict__ bhh,
    const float* __restrict__ h0,             // (B,512) fp32
    const float* __restrict__ c0,             // (B,512) fp32
    unsigned short* __restrict__ hbuf,        // 2 * B*512 bf16 ping-pong
    unsigned int* __restrict__ bars,          // 8*32 epoch flags (zeroed)
    float* __restrict__ cout,                 // (B,512) fp32 final c
    int write_seq)
{
  const int tid  = threadIdx.x;
  const int wave = tid >> 6;
  const int lane = tid & 63;
  const int lm   = lane & 15;
  const int quad = lane >> 4;

  const int bid = blockIdx.x;
  const int grp = bid & 7;
  const int kap = bid >> 3;
  const int bg0 = grp * 16;

  __shared__ float xpart[2][2][16][68];
  __shared__ float hpart[2][16][68];

  const int isH = (wave >= 2);
  const unsigned short* wsel = isH ? whh : wih;
  const int kbase = (wave & 1) * 256;

  s8v breg[4][8];
#pragma unroll
  for (int g = 0; g < 4; ++g) {
    const size_t row = (size_t)(g * 512 + kap * 16 + lm);
#pragma unroll
    for (int s = 0; s < 8; ++s)
      breg[g][s] = *(const s8v*)(wsel + row * HID + kbase + s * 32 + quad * 8);
  }

  const int b_i  = tid >> 4;
  const int kk   = tid & 15;
  const int kcol = kap * 16 + kk;
  const int brow = bg0 + b_i;

  float bias[4];
#pragma unroll
  for (int g = 0; g < 4; ++g) bias[g] = bih[g * 512 + kcol] + bhh[g * 512 + kcol];

  float c = c0[(size_t)brow * HID + kcol];

  {
    unsigned short hb0 = f2bf(h0[(size_t)brow * HID + kcol]);
    unsigned hw0 = (unsigned)hb0 | (((unsigned)(unsigned short)__shfl_xor((int)hb0, 1, 64)) << 16);
    if ((tid & 1) == 0)
      __hip_atomic_store((unsigned*)hbuf + (size_t)brow * (HID / 2) + (kcol >> 1),
                         hw0, __ATOMIC_RELAXED, __HIP_MEMORY_SCOPE_AGENT);
  }

  unsigned int* flags = bars + grp * 32;

  const int arow = bg0 + lm;
  const size_t xrowbase = (size_t)arow * TSEQ * HID;
  const int koffA = kbase + quad * 8;

  if (!isH) {
    const unsigned short* xb = xin + xrowbase + koffA;
    s8v af[8];
#pragma unroll
    for (int s = 0; s < 8; ++s) af[s] = *(const s8v*)(xb + s * 32);
    f4v acc[4];
#pragma unroll
    for (int g = 0; g < 4; ++g) { f4v z = {0.f, 0.f, 0.f, 0.f}; acc[g] = z; }
#pragma unroll
    for (int s = 0; s < 8; ++s)
#pragma unroll
      for (int g = 0; g < 4; ++g)
        acc[g] = __builtin_amdgcn_mfma_f32_16x16x32_bf16(af[s], breg[g][s], acc[g], 0, 0, 0);
#pragma unroll
    for (int g = 0; g < 4; ++g)
#pragma unroll
      for (int r = 0; r < 4; ++r)
        xpart[0][wave][quad * 4 + r][g * 16 + lm] = acc[g][r];
  }

  __syncthreads();
  if (tid == 0)
    __hip_atomic_store(&flags[kap], 1u, __ATOMIC_RELAXED, __HIP_MEMORY_SCOPE_AGENT);

  for (int t = 0; t < TSEQ; ++t) {
    if (!isH) {
      if (t + 1 < TSEQ) {
        const unsigned short* xb = xin + xrowbase + (size_t)(t + 1) * HID + koffA;
        s8v af[8];
#pragma unroll
        for (int s = 0; s < 8; ++s) af[s] = *(const s8v*)(xb + s * 32);
        f4v acc[4];
#pragma unroll
        for (int g = 0; g < 4; ++g) { f4v z = {0.f, 0.f, 0.f, 0.f}; acc[g] = z; }
#pragma unroll
        for (int s = 0; s < 8; ++s)
#pragma unroll
          for (int g = 0; g < 4; ++g)
            acc[g] = __builtin_amdgcn_mfma_f32_16x16x32_bf16(af[s], breg[g][s], acc[g], 0, 0, 0);
#pragma unroll
        for (int g = 0; g < 4; ++g)
#pragma unroll
          for (int r = 0; r < 4; ++r)
            xpart[(t + 1) & 1][wave][quad * 4 + r][g * 16 + lm] = acc[g][r];
      }
    } else {
      const unsigned tgt = (unsigned)(t + 1);
      for (int guard = 0; guard < (1 << 15); ++guard) {
        unsigned f = __hip_atomic_load(&flags[lane & 31], __ATOMIC_RELAXED,
                                       __HIP_MEMORY_SCOPE_AGENT);
        if (__all((int)(f >= tgt))) break;
      }
      asm volatile("" ::: "memory");
      const unsigned short* hprev = hbuf + (size_t)(t & 1) * BATCH * HID;
      const unsigned long long* hb64 =
          (const unsigned long long*)(hprev + (size_t)arow * HID + koffA);
      union { unsigned long long q[16]; s8v v[8]; } ua;
#pragma unroll
      for (int s = 0; s < 8; ++s) {
        ua.q[2 * s]     = __hip_atomic_load(hb64 + s * 8,     __ATOMIC_RELAXED, __HIP_MEMORY_SCOPE_AGENT);
        ua.q[2 * s + 1] = __hip_atomic_load(hb64 + s * 8 + 1, __ATOMIC_RELAXED, __HIP_MEMORY_SCOPE_AGENT);
      }
      f4v acc[4];
#pragma unroll
      for (int g = 0; g < 4; ++g) { f4v z = {0.f, 0.f, 0.f, 0.f}; acc[g] = z; }
#pragma unroll
      for (int s = 0; s < 8; ++s)
#pragma unroll
        for (int g = 0; g < 4; ++g)
          acc[g] = __builtin_amdgcn_mfma_f32_16x16x32_bf16(ua.v[s], breg[g][s], acc[g], 0, 0, 0);
#pragma unroll
      for (int g = 0; g < 4; ++g)
#pragma unroll
        for (int r = 0; r < 4; ++r)
          hpart[wave - 2][quad * 4 + r][g * 16 + lm] = acc[g][r];
    }

    __syncthreads();

    float gs[4];
#pragma unroll
    for (int g = 0; g < 4; ++g)
      gs[g] = bias[g]
            + xpart[t & 1][0][b_i][g * 16 + kk] + xpart[t & 1][1][b_i][g * 16 + kk]
            + hpart[0][b_i][g * 16 + kk]        + hpart[1][b_i][g * 16 + kk];

    float ig = fsig(gs[0]);
    float fg = fsig(gs[1]);
    float gg = ftanh(gs[2]);
    float og = fsig(gs[3]);
    c = fg * c + ig * gg;
    float h = og * ftanh(c);
    unsigned short hb = f2bf(h);

    unsigned hw = (unsigned)hb | (((unsigned)(unsigned short)__shfl_xor((int)hb, 1, 64)) << 16);
    unsigned short* hnext = hbuf + (size_t)((t & 1) ^ 1) * BATCH * HID;
    if ((tid & 1) == 0) {
      __hip_atomic_store((unsigned*)hnext + (size_t)brow * (HID / 2) + (kcol >> 1),
                         hw, __ATOMIC_RELAXED, __HIP_MEMORY_SCOPE_AGENT);
      if (write_seq)
        ((unsigned*)seqout)[((size_t)brow * TSEQ + t) * (HID / 2) + (kcol >> 1)] = hw;
    }

    __syncthreads();
    if (tid == 0)
      __hip_atomic_store(&flags[kap], (unsigned)(t + 2), __ATOMIC_RELAXED,
                         __HIP_MEMORY_SCOPE_AGENT);
  }

  cout[(size_t)brow * HID + kcol] = c;
}

extern "C" void kernel_launch(void* const* d_in, const int* in_sizes, int n_in,
                              void* d_out, int out_size, void* d_ws, size_t ws_size,
                              hipStream_t stream)
{
  (void)in_sizes; (void)n_in; (void)out_size;
  const float* x   = (const float*)d_in[0];
  const float* h0  = (const float*)d_in[1];
  const float* c0  = (const float*)d_in[2];
  const float* wih = (const float*)d_in[3];
  const float* whh = (const float*)d_in[4];
  const float* bih = (const float*)d_in[5];
  const float* bhh = (const float*)d_in[6];
  float* out = (float*)d_out;

  const size_t seq_elems  = (size_t)BATCH * TSEQ * HID;          // 67,108,864
  const size_t w_elems    = (size_t)LL * G4 * HID;               // 4,194,304
  const size_t ring_elems = (size_t)LL * RING * BATCH * HID;     // 2,097,152

  // R4 layout + shared flag region; coop ring overlays seqB (unused by coop).
  unsigned short* seqA  = (unsigned short*)d_ws;
  unsigned short* seqB  = seqA + seq_elems;
  unsigned short* wihb  = seqB + seq_elems;
  unsigned short* whhb  = wihb + w_elems;
  unsigned short* hbuf  = whhb + w_elems;                        // fallback only
  unsigned int*   bars  = (unsigned int*)(hbuf + 2 * (size_t)BATCH * HID);
  unsigned short* ringb = seqB;                                  // coop only
  (void)ring_elems;

  size_t need = (2 * seq_elems + 2 * w_elems + 2 * (size_t)BATCH * HID) * 2
              + (size_t)LL * NG * KAPS * 4;
  if (ws_size < need) return;  // fail visibly rather than corrupt memory

  cvt_f32_bf16<<<4096, 256, 0, stream>>>(x,   seqA, (int)(seq_elems / 4));
  cvt_f32_bf16<<<2048, 256, 0, stream>>>(wih, wihb, (int)(w_elems / 4));
  cvt_f32_bf16<<<2048, 256, 0, stream>>>(whh, whhb, (int)(w_elems / 4));

  // ---- capacity check for the 512-WG cooperative pipeline (cached) ----
  static int coop_capacity = -1;
  if (coop_capacity < 0) {
    int nb = 0, ncu = 0, dev = 0;
    hipGetDevice(&dev);
    hipOccupancyMaxActiveBlocksPerMultiprocessor(&nb, (const void*)lstm_all, 256, 0);
    hipDeviceGetAttribute(&ncu, hipDeviceAttributeMultiprocessorCount, dev);
    coop_capacity = nb * ncu;
  }

  bool done = false;
  if (coop_capacity >= LL * NG * KAPS) {
    hipMemsetAsync(bars, 0, LL * NG * KAPS * sizeof(unsigned), stream);
    const unsigned short* xp   = seqA;
    const unsigned short* wihp = wihb;
    const unsigned short* whhp = whhb;
    const float* bihp = bih;
    const float* bhhp = bhh;
    const float* h0p  = h0;
    const float* c0p  = c0;
    unsigned short* ringp = ringb;
    unsigned int*   barsp = bars;
    float* coutp = out;
    void* args[] = { &xp, &wihp, &whhp, &bihp, &bhhp, &h0p, &c0p,
                     &ringp, &barsp, &coutp };
    done = hipLaunchCooperativeKernel(lstm_all, dim3(LL * NG * KAPS), dim3(256),
                                      args, 0, stream) == hipSuccess;
  }

  if (!done) {
    // ---- proven R4 per-layer path ----
    for (int l = 0; l < LL; ++l) {
      hipMemsetAsync(bars, 0, 8 * 32 * sizeof(unsigned), stream);
      const unsigned short* in_p  = (l & 1) ? seqB : seqA;
      unsigned short*       out_p = (l & 1) ? seqA : seqB;
      const unsigned short* wih_p = wihb + (size_t)l * G4 * HID;
      const unsigned short* whh_p = whhb + (size_t)l * G4 * HID;
      const float* bih_p = bih + l * G4;
      const float* bhh_p = bhh + l * G4;
      const float* h0_p  = h0 + (size_t)l * BATCH * HID;
      const float* c0_p  = c0 + (size_t)l * BATCH * HID;
      float* cout_p = out + (size_t)l * BATCH * HID;
      int wsflag = (l < LL - 1) ? 1 : 0;
      unsigned short* hbuf_p = hbuf;
      unsigned int* bars_p = bars;
      void* args[] = { &in_p, &out_p, &wih_p, &whh_p, &bih_p, &bhh_p,
                       &h0_p, &c0_p, &hbuf_p, &bars_p, &cout_p, &wsflag };
      hipLaunchCooperativeKernel(lstm_layer, dim3(256), dim3(256), args, 0, stream);
    }
  }
}

// Round 3
// 10663.474 us; speedup vs baseline: 1.2730x; 1.2582x over previous
//
#include <hip/hip_runtime.h>
#include <stdint.h>

#define LL 4
#define BATCH 128
#define TSEQ 1024
#define HID 512
#define G4 2048
#define NG 2      // pipelined kernel: batch groups per layer (64 batches each)
#define BB 64     // pipelined kernel: batches per group (4 MFMA row-tiles)
#define KAPS 32   // hidden-slice WGs per group (16 cols each)
#define RING 8    // per-layer h ring depth (power of 2)

typedef __attribute__((ext_vector_type(8))) short s8v;   // 8 x bf16 fragment
typedef __attribute__((ext_vector_type(4))) float f4v;   // MFMA accumulator

__device__ __forceinline__ unsigned short f2bf(float f) {
  union { float f; unsigned u; } v; v.f = f;
  return (unsigned short)((v.u + 0x7fffu + ((v.u >> 16) & 1u)) >> 16);  // RNE
}

__device__ __forceinline__ float fsig(float x) { return 1.f / (1.f + __expf(-x)); }

__device__ __forceinline__ float ftanh(float x) {
  float a = __builtin_fabsf(x);
  float e = __expf(-2.f * a);
  float t = (1.f - e) / (1.f + e);
  return x < 0.f ? -t : t;
}

__global__ void cvt_f32_bf16(const float* __restrict__ in, unsigned short* __restrict__ out, int n4) {
  int stride = gridDim.x * blockDim.x;
  for (int i = blockIdx.x * blockDim.x + threadIdx.x; i < n4; i += stride) {
    f4v v = ((const f4v*)in)[i];
    union { unsigned short u[4]; unsigned long long d; } o;
    o.u[0] = f2bf(v.x); o.u[1] = f2bf(v.y); o.u[2] = f2bf(v.z); o.u[3] = f2bf(v.w);
    ((unsigned long long*)out)[i] = o.d;
  }
}

// Bounded flag spin with s_sleep backoff (cuts LLC spin traffic; detection
// granularity +~64cyc only). Guard expiry -> wrong answer, never a hang.
__device__ __forceinline__ void pollv(const unsigned int* p, int idx, int tgt) {
  unsigned f = __hip_atomic_load(&p[idx], __ATOMIC_RELAXED, __HIP_MEMORY_SCOPE_AGENT);
  if (!__all((int)f >= tgt)) {
    for (int guard = 0; guard < (1 << 17); ++guard) {
      __builtin_amdgcn_s_sleep(1);
      f = __hip_atomic_load(&p[idx], __ATOMIC_RELAXED, __HIP_MEMORY_SCOPE_AGENT);
      if (__all((int)f >= tgt)) break;
    }
  }
  asm volatile("" ::: "memory");  // no compiler motion of data loads above the poll
}

// One K=256 half of a 16-row GEMM fragment: 8 K-fragments x 4 gate-tiles.
template<bool ATOM>
__device__ __forceinline__ void mmfrag(const unsigned short* p, const s8v (&breg)[4][8], f4v (&acc)[4]) {
  union { unsigned long long q[16]; s8v v[8]; } ua;
  if (ATOM) {
    const unsigned long long* b64 = (const unsigned long long*)p;
#pragma unroll
    for (int s = 0; s < 8; ++s) {
      ua.q[2 * s]     = __hip_atomic_load(b64 + s * 8,     __ATOMIC_RELAXED, __HIP_MEMORY_SCOPE_AGENT);
      ua.q[2 * s + 1] = __hip_atomic_load(b64 + s * 8 + 1, __ATOMIC_RELAXED, __HIP_MEMORY_SCOPE_AGENT);
    }
  } else {
#pragma unroll
    for (int s = 0; s < 8; ++s) ua.v[s] = *(const s8v*)(p + s * 32);
  }
#pragma unroll
  for (int s = 0; s < 8; ++s)
#pragma unroll
    for (int g = 0; g < 4; ++g)
      acc[g] = __builtin_amdgcn_mfma_f32_16x16x32_bf16(ua.v[s], breg[g][s], acc[g], 0, 0, 0);
}

// Four 16-batch row tiles -> partial[64][64].
// D layout (m89): col = lane&15, row = quad*4 + reg.
// Bank swizzle: physical col = logical col ^ ((((row>>2)^row)&1)<<4).
//   writer: per store (bt,g,r2) the XOR bit = (quad^r2)&1 -> alternates across
//     quads -> 64 lanes split over both 16-bank windows = 2-way (free).
//   reader: XOR bit = ((bi>>2)^bi)&1; within a wave bi0 spans 4 consecutive
//     values -> bit0 alternates -> reads also 2-way. Same f(row) both sides.
template<bool ATOM>
__device__ __forceinline__ void gemm64(
    const unsigned short* __restrict__ base, size_t rstride,
    int bg0, int lm, int quad, int koffA,
    const s8v (&breg)[4][8], float (*dst)[64])
{
#pragma unroll
  for (int bt = 0; bt < 4; ++bt) {
    const unsigned short* p = base + (size_t)(bg0 + bt * 16 + lm) * rstride + koffA;
    f4v acc[4];
#pragma unroll
    for (int g = 0; g < 4; ++g) { f4v z = {0.f, 0.f, 0.f, 0.f}; acc[g] = z; }
    mmfrag<ATOM>(p, breg, acc);
#pragma unroll
    for (int g = 0; g < 4; ++g)
#pragma unroll
      for (int r2 = 0; r2 < 4; ++r2) {
        const int row = bt * 16 + quad * 4 + r2;
        const int swz = (((row >> 2) ^ row) & 1) << 4;
        dst[row][(g * 16 + lm) ^ swz] = acc[g][r2];
      }
  }
}

// All-4-layers pipelined persistent LSTM, 1 WG/CU.
//  256 WGs = 4 layers x 2 groups x 32 hidden slices; (lay,grp) = bid&7 so a
//  sync group's 32 WGs land on one XCD under round-robin dispatch (perf only).
//  waves 0-1 ("x waves"): compute x-partial for THIS step t; layers >=1 read
//    upstream ring slot t&7 gated by upf >= t+2 (upstream completed step t).
//  waves 2-3 ("h waves"): fused poll: lanes 0-31 ownf >= t+1 (group finished
//    step t-1); lanes 32-63 dnf >= t-6 (downstream finished step t-8, i.e.
//    its read of the slot t&7 we will overwrite).
//  Flag protocol (R2-verified): syncB drains all h stores (vmcnt(0)+s_barrier),
//    then tid0 stores flag = t+2 agent-scope.
__global__ void __launch_bounds__(256, 1) lstm_all(
    const unsigned short* __restrict__ xin,   // (B,T,512) bf16, layer-0 input
    const unsigned short* __restrict__ wihb,  // (L,2048,512) bf16
    const unsigned short* __restrict__ whhb,  // (L,2048,512) bf16
    const float* __restrict__ bih,            // (L,2048)
    const float* __restrict__ bhh,            // (L,2048)
    const float* __restrict__ h0,             // (L,B,512) fp32
    const float* __restrict__ c0,             // (L,B,512) fp32
    unsigned short* __restrict__ ring,        // L * RING * B * 512 bf16
    unsigned int* __restrict__ bars,          // L*NG*KAPS epoch flags (zeroed)
    float* __restrict__ cout)                 // (L,B,512) fp32 final c
{
  const int tid  = threadIdx.x;
  const int wave = tid >> 6;
  const int lane = tid & 63;
  const int lm   = lane & 15;
  const int quad = lane >> 4;

  const int bid = blockIdx.x;
  const int xg  = bid & 7;        // (lay,grp) -> XCD under round-robin
  const int lay = xg >> 1;
  const int grp = xg & 1;
  const int kap = bid >> 3;       // hidden slice 0..31
  const int bg0 = grp * BB;

  __shared__ float xpart[2][BB][64];   // [x wave][batch][gate] (current step)
  __shared__ float hpart[2][BB][64];   // [h wave][batch][gate]

  const int isH = (wave >= 2);
  const unsigned short* wsel = (isH ? whhb : wihb) + (size_t)lay * G4 * HID;
  const int kbase = (wave & 1) * 256;

  // ---- weight fragments resident for all 1024 steps ----
  s8v breg[4][8];
#pragma unroll
  for (int g = 0; g < 4; ++g) {
    const size_t row = (size_t)(g * 512 + kap * 16 + lm);
#pragma unroll
    for (int s = 0; s < 8; ++s)
      breg[g][s] = *(const s8v*)(wsel + row * HID + kbase + s * 32 + quad * 8);
  }

  // ---- per-thread cell ownership: 4 cells (bi0 + 16j) x col kcol ----
  const int bi0  = tid >> 4;      // 0..15
  const int kk   = tid & 15;
  const int kcol = kap * 16 + kk;

  float bias[4];
#pragma unroll
  for (int g = 0; g < 4; ++g)
    bias[g] = bih[lay * G4 + g * 512 + kcol] + bhh[lay * G4 + g * 512 + kcol];

  unsigned short* ringL = ring + (size_t)lay * RING * BATCH * HID;
  const unsigned short* ringUp = ring + (size_t)(lay - 1) * RING * BATCH * HID;

  // publish h0 = h(-1) into ring slot RING-1 through the coherence point
  float c[4];
#pragma unroll
  for (int j = 0; j < 4; ++j) {
    const int brow = bg0 + bi0 + j * 16;
    c[j] = c0[(size_t)lay * BATCH * HID + (size_t)brow * HID + kcol];
    unsigned short hb0 = f2bf(h0[(size_t)lay * BATCH * HID + (size_t)brow * HID + kcol]);
    unsigned hw0 = (unsigned)hb0 | (((unsigned)(unsigned short)__shfl_xor((int)hb0, 1, 64)) << 16);
    if ((tid & 1) == 0)
      __hip_atomic_store((unsigned*)(ringL + (size_t)(RING - 1) * BATCH * HID)
                             + (size_t)brow * (HID / 2) + (kcol >> 1),
                         hw0, __ATOMIC_RELAXED, __HIP_MEMORY_SCOPE_AGENT);
  }

  unsigned int* ownf = bars + (xg << 5);
  unsigned int* upf  = ownf - (NG << 5);   // deref'd only lay>0
  unsigned int* dnf  = ownf + (NG << 5);   // deref'd only lay<LL-1

  const int koffA = kbase + quad * 8;

  __syncthreads();                   // drains h0 stores of every wave
  if (tid == 0)
    __hip_atomic_store(&ownf[kap], 1u, __ATOMIC_RELAXED, __HIP_MEMORY_SCOPE_AGENT);

  for (int t = 0; t < TSEQ; ++t) {
    if (!isH) {
      // ---- x waves: partial for step t (parallel with h waves' poll+GEMM) ----
      if (lay > 0) {
        pollv(upf, lane & 31, t + 2);   // upstream completed step t -> h_up(t) ready
        gemm64<true>(ringUp + (size_t)(t & (RING - 1)) * BATCH * HID,
                     (size_t)HID, bg0, lm, quad, koffA, breg, xpart[wave]);
      } else {
        gemm64<false>(xin + (size_t)t * HID, (size_t)TSEQ * HID,
                      bg0, lm, quad, koffA, breg, xpart[wave]);
      }
    } else {
      // ---- h waves: fused poll (own epoch + downstream back-pressure) ----
      const bool ownside = (lane < 32) || (lay == LL - 1);
      pollv(ownside ? ownf : dnf, lane & 31, ownside ? (t + 1) : (t - 6));
      gemm64<true>(ringL + (size_t)((t - 1) & (RING - 1)) * BATCH * HID,
                   (size_t)HID, bg0, lm, quad, koffA, breg, hpart[wave - 2]);
    }

    __syncthreads();   // sync A: partials visible; all polls passed

    unsigned short hbv[4];
#pragma unroll
    for (int j = 0; j < 4; ++j) {
      const int bi = bi0 + j * 16;
      const int swz = ((((bi >> 2) ^ bi) & 1) << 4);
      float gs[4];
#pragma unroll
      for (int g = 0; g < 4; ++g) {
        const int col = (g * 16 + kk) ^ swz;
        gs[g] = bias[g]
              + xpart[0][bi][col] + xpart[1][bi][col]
              + hpart[0][bi][col] + hpart[1][bi][col];
      }
      float ig = fsig(gs[0]);
      float fg = fsig(gs[1]);
      float gg = ftanh(gs[2]);
      float og = fsig(gs[3]);
      c[j] = fg * c[j] + ig * gg;
      hbv[j] = f2bf(og * ftanh(c[j]));
    }

    // publish h(t) into ring slot t&7 (recurrent readers + downstream layer)
    unsigned short* hdst = ringL + (size_t)(t & (RING - 1)) * BATCH * HID;
#pragma unroll
    for (int j = 0; j < 4; ++j) {
      unsigned hw = (unsigned)hbv[j] | (((unsigned)(unsigned short)__shfl_xor((int)hbv[j], 1, 64)) << 16);
      if ((tid & 1) == 0)
        __hip_atomic_store((unsigned*)hdst + (size_t)(bg0 + bi0 + j * 16) * (HID / 2) + (kcol >> 1),
                           hw, __ATOMIC_RELAXED, __HIP_MEMORY_SCOPE_AGENT);
    }

    __syncthreads();   // sync B: every wave's h stores drained (vmcnt(0)+s_barrier)
    if (tid == 0)
      __hip_atomic_store(&ownf[kap], (unsigned)(t + 2), __ATOMIC_RELAXED,
                         __HIP_MEMORY_SCOPE_AGENT);
  }

#pragma unroll
  for (int j = 0; j < 4; ++j)
    cout[(size_t)lay * BATCH * HID + (size_t)(bg0 + bi0 + j * 16) * HID + kcol] = c[j];
}

// ---------------------------------------------------------------------------
// Fallback: the proven R4 per-layer kernel (verbatim; passes at ~13.4 ms).
// Used only if the cooperative capacity check / launch denies the pipelined
// kernel (e.g. 64KB static LDS rejected).
// ---------------------------------------------------------------------------
__global__ void __launch_bounds__(256, 1) lstm_layer(
    const unsigned short* __restrict__ xin,
    unsigned short* __restrict__ seqout,
    const unsigned short* __restrict__ wih,
    const unsigned short* __restrict__ whh,
    const float* __restrict__ bih,
    const float* __restrict__ bhh,
    const float* __restrict__ h0,
    const float* __restrict__ c0,
    unsigned short* __restrict__ hbuf,
    unsigned int* __restrict__ bars,
    float* __restrict__ cout,
    int write_seq)
{
  const int tid  = threadIdx.x;
  const int wave = tid >> 6;
  const int lane = tid & 63;
  const int lm   = lane & 15;
  const int quad = lane >> 4;

  const int bid = blockIdx.x;
  const int grp = bid & 7;
  const int kap = bid >> 3;
  const int bg0 = grp * 16;

  __shared__ float xpart[2][2][16][68];
  __shared__ float hpart[2][16][68];

  const int isH = (wave >= 2);
  const unsigned short* wsel = isH ? whh : wih;
  const int kbase = (wave & 1) * 256;

  s8v breg[4][8];
#pragma unroll
  for (int g = 0; g < 4; ++g) {
    const size_t row = (size_t)(g * 512 + kap * 16 + lm);
#pragma unroll
    for (int s = 0; s < 8; ++s)
      breg[g][s] = *(const s8v*)(wsel + row * HID + kbase + s * 32 + quad * 8);
  }

  const int b_i  = tid >> 4;
  const int kk   = tid & 15;
  const int kcol = kap * 16 + kk;
  const int brow = bg0 + b_i;

  float bias[4];
#pragma unroll
  for (int g = 0; g < 4; ++g) bias[g] = bih[g * 512 + kcol] + bhh[g * 512 + kcol];

  float c = c0[(size_t)brow * HID + kcol];

  {
    unsigned short hb0 = f2bf(h0[(size_t)brow * HID + kcol]);
    unsigned hw0 = (unsigned)hb0 | (((unsigned)(unsigned short)__shfl_xor((int)hb0, 1, 64)) << 16);
    if ((tid & 1) == 0)
      __hip_atomic_store((unsigned*)hbuf + (size_t)brow * (HID / 2) + (kcol >> 1),
                         hw0, __ATOMIC_RELAXED, __HIP_MEMORY_SCOPE_AGENT);
  }

  unsigned int* flags = bars + grp * 32;

  const int arow = bg0 + lm;
  const size_t xrowbase = (size_t)arow * TSEQ * HID;
  const int koffA = kbase + quad * 8;

  if (!isH) {
    const unsigned short* xb = xin + xrowbase + koffA;
    s8v af[8];
#pragma unroll
    for (int s = 0; s < 8; ++s) af[s] = *(const s8v*)(xb + s * 32);
    f4v acc[4];
#pragma unroll
    for (int g = 0; g < 4; ++g) { f4v z = {0.f, 0.f, 0.f, 0.f}; acc[g] = z; }
#pragma unroll
    for (int s = 0; s < 8; ++s)
#pragma unroll
      for (int g = 0; g < 4; ++g)
        acc[g] = __builtin_amdgcn_mfma_f32_16x16x32_bf16(af[s], breg[g][s], acc[g], 0, 0, 0);
#pragma unroll
    for (int g = 0; g < 4; ++g)
#pragma unroll
      for (int r = 0; r < 4; ++r)
        xpart[0][wave][quad * 4 + r][g * 16 + lm] = acc[g][r];
  }

  __syncthreads();
  if (tid == 0)
    __hip_atomic_store(&flags[kap], 1u, __ATOMIC_RELAXED, __HIP_MEMORY_SCOPE_AGENT);

  for (int t = 0; t < TSEQ; ++t) {
    if (!isH) {
      if (t + 1 < TSEQ) {
        const unsigned short* xb = xin + xrowbase + (size_t)(t + 1) * HID + koffA;
        s8v af[8];
#pragma unroll
        for (int s = 0; s < 8; ++s) af[s] = *(const s8v*)(xb + s * 32);
        f4v acc[4];
#pragma unroll
        for (int g = 0; g < 4; ++g) { f4v z = {0.f, 0.f, 0.f, 0.f}; acc[g] = z; }
#pragma unroll
        for (int s = 0; s < 8; ++s)
#pragma unroll
          for (int g = 0; g < 4; ++g)
            acc[g] = __builtin_amdgcn_mfma_f32_16x16x32_bf16(af[s], breg[g][s], acc[g], 0, 0, 0);
#pragma unroll
        for (int g = 0; g < 4; ++g)
#pragma unroll
          for (int r = 0; r < 4; ++r)
            xpart[(t + 1) & 1][wave][quad * 4 + r][g * 16 + lm] = acc[g][r];
      }
    } else {
      const unsigned tgt = (unsigned)(t + 1);
      for (int guard = 0; guard < (1 << 15); ++guard) {
        unsigned f = __hip_atomic_load(&flags[lane & 31], __ATOMIC_RELAXED,
                                       __HIP_MEMORY_SCOPE_AGENT);
        if (__all((int)(f >= tgt))) break;
      }
      asm volatile("" ::: "memory");
      const unsigned short* hprev = hbuf + (size_t)(t & 1) * BATCH * HID;
      const unsigned long long* hb64 =
          (const unsigned long long*)(hprev + (size_t)arow * HID + koffA);
      union { unsigned long long q[16]; s8v v[8]; } ua;
#pragma unroll
      for (int s = 0; s < 8; ++s) {
        ua.q[2 * s]     = __hip_atomic_load(hb64 + s * 8,     __ATOMIC_RELAXED, __HIP_MEMORY_SCOPE_AGENT);
        ua.q[2 * s + 1] = __hip_atomic_load(hb64 + s * 8 + 1, __ATOMIC_RELAXED, __HIP_MEMORY_SCOPE_AGENT);
      }
      f4v acc[4];
#pragma unroll
      for (int g = 0; g < 4; ++g) { f4v z = {0.f, 0.f, 0.f, 0.f}; acc[g] = z; }
#pragma unroll
      for (int s = 0; s < 8; ++s)
#pragma unroll
        for (int g = 0; g < 4; ++g)
          acc[g] = __builtin_amdgcn_mfma_f32_16x16x32_bf16(ua.v[s], breg[g][s], acc[g], 0, 0, 0);
#pragma unroll
      for (int g = 0; g < 4; ++g)
#pragma unroll
        for (int r = 0; r < 4; ++r)
          hpart[wave - 2][quad * 4 + r][g * 16 + lm] = acc[g][r];
    }

    __syncthreads();

    float gs[4];
#pragma unroll
    for (int g = 0; g < 4; ++g)
      gs[g] = bias[g]
            + xpart[t & 1][0][b_i][g * 16 + kk] + xpart[t & 1][1][b_i][g * 16 + kk]
            + hpart[0][b_i][g * 16 + kk]        + hpart[1][b_i][g * 16 + kk];

    float ig = fsig(gs[0]);
    float fg = fsig(gs[1]);
    float gg = ftanh(gs[2]);
    float og = fsig(gs[3]);
    c = fg * c + ig * gg;
    float h = og * ftanh(c);
    unsigned short hb = f2bf(h);

    unsigned hw = (unsigned)hb | (((unsigned)(unsigned short)__shfl_xor((int)hb, 1, 64)) << 16);
    unsigned short* hnext = hbuf + (size_t)((t & 1) ^ 1) * BATCH * HID;
    if ((tid & 1) == 0) {
      __hip_atomic_store((unsigned*)hnext + (size_t)brow * (HID / 2) + (kcol >> 1),
                         hw, __ATOMIC_RELAXED, __HIP_MEMORY_SCOPE_AGENT);
      if (write_seq)
        ((unsigned*)seqout)[((size_t)brow * TSEQ + t) * (HID / 2) + (kcol >> 1)] = hw;
    }

    __syncthreads();
    if (tid == 0)
      __hip_atomic_store(&flags[kap], (unsigned)(t + 2), __ATOMIC_RELAXED,
                         __HIP_MEMORY_SCOPE_AGENT);
  }

  cout[(size_t)brow * HID + kcol] = c;
}

extern "C" void kernel_launch(void* const* d_in, const int* in_sizes, int n_in,
                              void* d_out, int out_size, void* d_ws, size_t ws_size,
                              hipStream_t stream)
{
  (void)in_sizes; (void)n_in; (void)out_size;
  const float* x   = (const float*)d_in[0];
  const float* h0  = (const float*)d_in[1];
  const float* c0  = (const float*)d_in[2];
  const float* wih = (const float*)d_in[3];
  const float* whh = (const float*)d_in[4];
  const float* bih = (const float*)d_in[5];
  const float* bhh = (const float*)d_in[6];
  float* out = (float*)d_out;

  const size_t seq_elems  = (size_t)BATCH * TSEQ * HID;          // 67,108,864
  const size_t w_elems    = (size_t)LL * G4 * HID;               // 4,194,304
  const size_t ring_elems = (size_t)LL * RING * BATCH * HID;     // 2,097,152

  // R4 layout + shared flag region; coop ring overlays seqB (unused by coop).
  unsigned short* seqA  = (unsigned short*)d_ws;
  unsigned short* seqB  = seqA + seq_elems;
  unsigned short* wihb  = seqB + seq_elems;
  unsigned short* whhb  = wihb + w_elems;
  unsigned short* hbuf  = whhb + w_elems;                        // fallback only
  unsigned int*   bars  = (unsigned int*)(hbuf + 2 * (size_t)BATCH * HID);
  unsigned short* ringb = seqB;                                  // coop only
  (void)ring_elems;

  size_t need = (2 * seq_elems + 2 * w_elems + 2 * (size_t)BATCH * HID) * 2
              + (size_t)LL * NG * KAPS * 4;
  if (ws_size < need) return;  // fail visibly rather than corrupt memory

  cvt_f32_bf16<<<4096, 256, 0, stream>>>(x,   seqA, (int)(seq_elems / 4));
  cvt_f32_bf16<<<2048, 256, 0, stream>>>(wih, wihb, (int)(w_elems / 4));
  cvt_f32_bf16<<<2048, 256, 0, stream>>>(whh, whhb, (int)(w_elems / 4));

  // ---- capacity check for the 256-WG cooperative pipeline (cached) ----
  static int coop_capacity = -1;
  if (coop_capacity < 0) {
    int nb = 0, ncu = 0, dev = 0;
    hipGetDevice(&dev);
    hipOccupancyMaxActiveBlocksPerMultiprocessor(&nb, (const void*)lstm_all, 256, 0);
    hipDeviceGetAttribute(&ncu, hipDeviceAttributeMultiprocessorCount, dev);
    coop_capacity = nb * ncu;
  }

  bool done = false;
  if (coop_capacity >= LL * NG * KAPS) {
    hipMemsetAsync(bars, 0, LL * NG * KAPS * sizeof(unsigned), stream);
    const unsigned short* xp   = seqA;
    const unsigned short* wihp = wihb;
    const unsigned short* whhp = whhb;
    const float* bihp = bih;
    const float* bhhp = bhh;
    const float* h0p  = h0;
    const float* c0p  = c0;
    unsigned short* ringp = ringb;
    unsigned int*   barsp = bars;
    float* coutp = out;
    void* args[] = { &xp, &wihp, &whhp, &bihp, &bhhp, &h0p, &c0p,
                     &ringp, &barsp, &coutp };
    done = hipLaunchCooperativeKernel(lstm_all, dim3(LL * NG * KAPS), dim3(256),
                                      args, 0, stream) == hipSuccess;
  }

  if (!done) {
    // ---- proven R4 per-layer path ----
    for (int l = 0; l < LL; ++l) {
      hipMemsetAsync(bars, 0, 8 * 32 * sizeof(unsigned), stream);
      const unsigned short* in_p  = (l & 1) ? seqB : seqA;
      unsigned short*       out_p = (l & 1) ? seqA : seqB;
      const unsigned short* wih_p = wihb + (size_t)l * G4 * HID;
      const unsigned short* whh_p = whhb + (size_t)l * G4 * HID;
      const float* bih_p = bih + l * G4;
      const float* bhh_p = bhh + l * G4;
      const float* h0_p  = h0 + (size_t)l * BATCH * HID;
      const float* c0_p  = c0 + (size_t)l * BATCH * HID;
      float* cout_p = out + (size_t)l * BATCH * HID;
      int wsflag = (l < LL - 1) ? 1 : 0;
      unsigned short* hbuf_p = hbuf;
      unsigned int* bars_p = bars;
      void* args[] = { &in_p, &out_p, &wih_p, &whh_p, &bih_p, &bhh_p,
                       &h0_p, &c0_p, &hbuf_p, &bars_p, &cout_p, &wsflag };
      hipLaunchCooperativeKernel(lstm_layer, dim3(256), dim3(256), args, 0, stream);
    }
  }
}